// Round 9
// baseline (263.621 us; speedup 1.0000x reference)
//
#include <hip/hip_runtime.h>
#include <stdint.h>

#define B_   2
#define C_   512
#define N_   4096           // 64*64 pixels
#define G_   8
#define NH_  8
#define HD_  64
#define GRPELEMS ((C_ / G_) * N_)   // 262144 per (b, group)
#define NCHUNK 16                   // partial-reduce chunks per (b, group)

typedef __bf16 bf16x8 __attribute__((ext_vector_type(8)));
typedef float  f32x4  __attribute__((ext_vector_type(4)));

#if __has_builtin(__builtin_amdgcn_exp2f)
#define EXP2(x) __builtin_amdgcn_exp2f(x)
#else
#define EXP2(x) exp2f(x)
#endif

// fp32 -> bf16 round-to-nearest-even (finite inputs only)
__device__ inline unsigned f2bf(float f) {
    union { float f; unsigned u; } v; v.f = f;
    return (v.u + 0x7FFFu + ((v.u >> 16) & 1u)) >> 16;
}
__device__ inline __bf16 tobf(float f) {
    unsigned short u = (unsigned short)f2bf(f);
    union { unsigned short u; __bf16 b; } c; c.u = u;
    return c.b;
}
// pack hi16(f1):hi16(f0) in ONE v_perm_b32 (truncation to bf16)
__device__ inline unsigned pktrunc(float f0, float f1) {
    return __builtin_amdgcn_perm(__float_as_uint(f1), __float_as_uint(f0),
                                 0x07060302u);
}

// async global->LDS, 16B per lane; LDS dest = wave-uniform base + lane*16
#define GLOAD16(g, l)                                                     \
    __builtin_amdgcn_global_load_lds(                                     \
        (const __attribute__((address_space(1))) unsigned*)(g),           \
        (__attribute__((address_space(3))) unsigned*)(l), 16, 0, 0)

// ---------------------------------------------------------------------------
// prep: fused GroupNorm partial stats + weight bf16 conversion.
// ---------------------------------------------------------------------------
__global__ __launch_bounds__(256) void prep(const float* __restrict__ x,
                                            const float* __restrict__ qw,
                                            const float* __restrict__ pw,
                                            float* __restrict__ psum,
                                            float* __restrict__ psq,
                                            __bf16* __restrict__ dq,
                                            __bf16* __restrict__ dp) {
    const int blk = blockIdx.x;
    const int t = threadIdx.x;
    if (blk < 256) {
        const float4* p = (const float4*)x + (size_t)blk * 4096;
        float s = 0.f, s2 = 0.f;
#pragma unroll
        for (int i = 0; i < 16; ++i) {
            float4 v = p[t + (i << 8)];
            s  += v.x + v.y + v.z + v.w;
            s2 += v.x * v.x + v.y * v.y + v.z * v.z + v.w * v.w;
        }
#pragma unroll
        for (int off = 1; off < 64; off <<= 1) {
            s  += __shfl_xor(s, off);
            s2 += __shfl_xor(s2, off);
        }
        __shared__ float rs[4], rq[4];
        if ((t & 63) == 0) { rs[t >> 6] = s; rq[t >> 6] = s2; }
        __syncthreads();
        if (t == 0) {
            psum[blk] = rs[0] + rs[1] + rs[2] + rs[3];
            psq[blk]  = rq[0] + rq[1] + rq[2] + rq[3];
        }
    } else {
        const int QW4 = (3 * C_ * C_) / 4;   // 196608 float4s
        int idx = (blk - 256) * 256 + t;
        float4 v; __bf16* dst; int o;
        if (idx < QW4) { v = ((const float4*)qw)[idx]; dst = dq; o = idx; }
        else           { v = ((const float4*)pw)[idx - QW4]; dst = dp; o = idx - QW4; }
        uint2 pk;
        pk.x = f2bf(v.x) | (f2bf(v.y) << 16);
        pk.y = f2bf(v.z) | (f2bf(v.w) << 16);
        *(uint2*)(dst + (size_t)o * 4) = pk;
    }
}

// ---------------------------------------------------------------------------
// GroupNorm finalize + apply + transpose: x[b][c][p] fp32 -> xnT[b][p][c] bf16.
// ---------------------------------------------------------------------------
__global__ __launch_bounds__(256) void gn_apply_t(const float* __restrict__ x,
                                                  const float* __restrict__ w,
                                                  const float* __restrict__ bb,
                                                  const float* __restrict__ psum,
                                                  const float* __restrict__ psq,
                                                  __bf16* __restrict__ xnT) {
    const int p0 = blockIdx.x << 6, c0 = blockIdx.y << 6, b = blockIdx.z;
    __shared__ __bf16 T[64][76];   // row stride 152 B
    __shared__ float red[2 * NCHUNK];
    __shared__ float smr[2];
    const int tid = threadIdx.x;
    const int bg = b * G_ + (c0 >> 6);

    if (tid < NCHUNK)            red[tid] = psum[bg * NCHUNK + tid];
    else if (tid < 2 * NCHUNK)   red[tid] = psq[bg * NCHUNK + tid - NCHUNK];
    __syncthreads();
    if (tid == 0) {
        float s = 0.f, q = 0.f;
#pragma unroll
        for (int i = 0; i < NCHUNK; ++i) { s += red[i]; q += red[NCHUNK + i]; }
        const float inv = 1.f / (float)GRPELEMS;
        float mean = s * inv;
        float var  = q * inv - mean * mean;
        smr[0] = mean;
        smr[1] = rsqrtf(var + 1e-5f);
    }
    __syncthreads();
    const float mean = smr[0], rstd = smr[1];

    const int tr  = tid >> 4;
    const int tc4 = (tid & 15) << 2;
    const float* xb = x + ((size_t)b * C_ + c0) * N_ + p0;
#pragma unroll
    for (int cc = tr; cc < 64; cc += 16) {
        int c = c0 + cc;
        float sc = rstd * w[c];
        float sh = bb[c] - mean * sc;
        float4 v = *(const float4*)(xb + (size_t)cc * N_ + tc4);
        T[tc4 + 0][cc] = tobf(v.x * sc + sh);
        T[tc4 + 1][cc] = tobf(v.y * sc + sh);
        T[tc4 + 2][cc] = tobf(v.z * sc + sh);
        T[tc4 + 3][cc] = tobf(v.w * sc + sh);
    }
    __syncthreads();
    __bf16* dst = xnT + ((size_t)b * N_ + p0) * C_ + c0;
#pragma unroll
    for (int pp = tr; pp < 64; pp += 16)
        *(uint2*)(dst + (size_t)pp * C_ + tc4) = *(const uint2*)&T[pp][tc4];
}

// ---------------------------------------------------------------------------
// bf16 MFMA GEMM: C[o][p] = sum_c A[o][c]*Bm[b][p][c]
// EPI 0 epilogue writes MFMA-A-operand-ready BLOCKED K/V layouts (8 KB per
// 64-key block so the attn loop advances one uniform pointer per iter):
//   q: qT[bh][p][d]                      (pre-scaled)
//   k: kP[bh][key>>6][d>>3][key&63][8]   (granule = 8 d)
//   v: vP[bh][key>>6][(key>>3)&7][d][8]  (granule = 8 keys)
// ---------------------------------------------------------------------------
template <int M_TOTAL, int EPI>
__global__ __launch_bounds__(256) void gemm_bf16(const __bf16* __restrict__ A,
                                                 const __bf16* __restrict__ Bm,
                                                 const float* __restrict__ bias,
                                                 const float* __restrict__ resid,
                                                 __bf16* __restrict__ qT,
                                                 __bf16* __restrict__ kP,
                                                 __bf16* __restrict__ vP,
                                                 float* __restrict__ Y) {
    const int b  = blockIdx.z;
    const int M0 = blockIdx.y << 7;
    const int N0 = blockIdx.x << 7;
    const int tid = threadIdx.x;
    const int w = tid >> 6, lane = tid & 63;
    const int quad = lane >> 4, l16 = lane & 15;
    const int wr = w >> 1, wc = w & 1;

    __shared__ __bf16 As[128 * 64];
    __shared__ __bf16 Bs[128 * 64];

    const __bf16* Bb = Bm + (size_t)b * ((size_t)N_ * C_);

    const int srow = lane >> 3;
    const int sg   = lane & 7;

    f32x4 acc[4][4];
#pragma unroll
    for (int mt = 0; mt < 4; ++mt)
#pragma unroll
        for (int nt = 0; nt < 4; ++nt) acc[mt][nt] = (f32x4){0.f, 0.f, 0.f, 0.f};

    for (int k0 = 0; k0 < C_; k0 += 64) {
        __syncthreads();
#pragma unroll
        for (int i = 0; i < 4; ++i) {
            int r  = (w << 5) + (i << 3) + srow;
            int gc = ((sg ^ (r & 7)) << 3);
            const __bf16* ga = A  + (size_t)(M0 + r) * C_ + k0 + gc;
            const __bf16* gb = Bb + (size_t)(N0 + r) * C_ + k0 + gc;
            GLOAD16(ga, As + (((w << 2) + i) << 9));
            GLOAD16(gb, Bs + (((w << 2) + i) << 9));
        }
        __syncthreads();

#pragma unroll
        for (int kk = 0; kk < 2; ++kk) {
            bf16x8 af[4], bfr[4];
            const int gk = (kk << 2) + quad;
#pragma unroll
            for (int mt = 0; mt < 4; ++mt) {
                int m = (wr << 6) + (mt << 4) + l16;
                af[mt] = *(const bf16x8*)&As[(m << 6) + ((gk ^ (m & 7)) << 3)];
            }
#pragma unroll
            for (int nt = 0; nt < 4; ++nt) {
                int n = (wc << 6) + (nt << 4) + l16;
                bfr[nt] = *(const bf16x8*)&Bs[(n << 6) + ((gk ^ (n & 7)) << 3)];
            }
#pragma unroll
            for (int mt = 0; mt < 4; ++mt)
#pragma unroll
                for (int nt = 0; nt < 4; ++nt)
                    acc[mt][nt] = __builtin_amdgcn_mfma_f32_16x16x32_bf16(
                        af[mt], bfr[nt], acc[mt][nt], 0, 0, 0);
        }
    }

    if (EPI == 0) {
        const int t = M0 >> 9;
        const float sc = (t == 0) ? (0.125f * 1.44269504f) : 1.f;
#pragma unroll
        for (int mt = 0; mt < 4; ++mt) {
            const int o0 = M0 + (wr << 6) + (mt << 4) + (quad << 2);
            const int h  = (o0 >> 6) & 7;
            const int d0 = o0 & 63;
            const size_t bh = (size_t)b * NH_ + h;
            float bi[4];
#pragma unroll
            for (int r = 0; r < 4; ++r) bi[r] = bias[o0 + r];
            if (t == 0) {
                __bf16* dst = qT + (bh * N_) * HD_ + d0;
#pragma unroll
                for (int nt = 0; nt < 4; ++nt) {
                    int p = N0 + (wc << 6) + (nt << 4) + l16;
                    f32x4 v = acc[mt][nt];
                    uint2 pk;
                    pk.x = f2bf((v[0] + bi[0]) * sc) | (f2bf((v[1] + bi[1]) * sc) << 16);
                    pk.y = f2bf((v[2] + bi[2]) * sc) | (f2bf((v[3] + bi[3]) * sc) << 16);
                    *(uint2*)(dst + (size_t)p * HD_) = pk;
                }
            } else if (t == 1) {
                // K''[key>>6][d0>>3][key&63][8]; d0&7 in {0,4}
                __bf16* dst = kP + bh * ((size_t)N_ * HD_);
#pragma unroll
                for (int nt = 0; nt < 4; ++nt) {
                    int p = N0 + (wc << 6) + (nt << 4) + l16;
                    f32x4 v = acc[mt][nt];
                    uint2 pk;
                    pk.x = f2bf(v[0] + bi[0]) | (f2bf(v[1] + bi[1]) << 16);
                    pk.y = f2bf(v[2] + bi[2]) | (f2bf(v[3] + bi[3]) << 16);
                    size_t off = (size_t)(p >> 6) * 4096 +
                                 (size_t)((d0 >> 3) * 64 + (p & 63)) * 8 + (d0 & 7);
                    *(uint2*)(dst + off) = pk;
                }
            } else {
                // V''[key>>6][(key>>3)&7][d][8]
                __bf16* dst = vP + bh * ((size_t)HD_ * N_);
#pragma unroll
                for (int nt = 0; nt < 4; ++nt) {
                    int p = N0 + (wc << 6) + (nt << 4) + l16;
                    size_t base = (size_t)(p >> 6) * 4096 +
                                  (size_t)(((p >> 3) & 7) * 64) * 8 + (p & 7);
                    f32x4 v = acc[mt][nt];
#pragma unroll
                    for (int r = 0; r < 4; ++r)
                        dst[base + (size_t)(d0 + r) * 8] = tobf(v[r] + bi[r]);
                }
            }
        }
    } else {
#pragma unroll
        for (int mt = 0; mt < 4; ++mt) {
            const int o0 = M0 + (wr << 6) + (mt << 4) + (quad << 2);
            float bi[4];
#pragma unroll
            for (int r = 0; r < 4; ++r) bi[r] = bias[o0 + r];
#pragma unroll
            for (int nt = 0; nt < 4; ++nt) {
                int p = N0 + (wc << 6) + (nt << 4) + l16;
                f32x4 v = acc[mt][nt];
#pragma unroll
                for (int r = 0; r < 4; ++r) {
                    size_t off = ((size_t)b * C_ + o0 + r) * N_ + p;
                    Y[off] = v[r] + bi[r] + resid[off];
                }
            }
        }
    }
}

// ---------------------------------------------------------------------------
// MFMA flash attention v5: 16 q/wave, 4 waves/block (64 q/block), no barriers.
//  - K/V from blocked operand layouts: per iter ONE uniform pointer advance
//    (+4096 elem); every load = base + loop-invariant lane voffset + imm.
//  - l via constant-ones-A MFMA on the packed P (consistent + zero VALU).
//  - LDS: only per-wave Ps round-trip (8 KB), verified swizzle formulas.
// ---------------------------------------------------------------------------
__global__ __launch_bounds__(256) void attn_mfma(const __bf16* __restrict__ qT,
                                                 const __bf16* __restrict__ kP,
                                                 const __bf16* __restrict__ vP,
                                                 __bf16* __restrict__ attT) {
    const int tid  = threadIdx.x;
    const int w    = tid >> 6;
    const int lane = tid & 63;
    const int quad = lane >> 4;
    const int l16  = lane & 15;
    const int l7   = l16 & 7;
    const int h = blockIdx.y, b = blockIdx.z;
    const int qw0 = (blockIdx.x << 6) + (w << 4);   // 16 q per wave

    __shared__ __bf16 Ps[4][16][64];   // per-wave P^T [q][key], 8B-granule swz

    const size_t bh = (size_t)b * NH_ + h;
    const __bf16* qTb = qT + bh * ((size_t)N_ * HD_);
    const __bf16* kblk = kP + bh * ((size_t)N_ * HD_);
    const __bf16* vblk = vP + bh * ((size_t)HD_ * N_);

    // loop-invariant lane voffsets into an 8 KB block (shared by K and V)
    const int voff0 = (quad * 64 + l16) * 8;         // hh/h2 = 0
    const int voff1 = ((4 + quad) * 64 + l16) * 8;   // hh/h2 = 1

    // Q fragments: persistent (q pre-scaled); B-operand n=l16, k=quad*8+j+32hh
    bf16x8 qf[2];
#pragma unroll
    for (int hh = 0; hh < 2; ++hh)
        qf[hh] = *(const bf16x8*)(qTb +
            (size_t)(qw0 + l16) * HD_ + (hh << 5) + (quad << 3));

    // constant ones A-fragment (16x32 all-ones matrix slice per lane)
    bf16x8 ones;
#pragma unroll
    for (int i = 0; i < 8; ++i) ones[i] = (__bf16)1.0f;

    const f32x4 zero4 = {0.f, 0.f, 0.f, 0.f};
    f32x4 o[4];
#pragma unroll
    for (int dt = 0; dt < 4; ++dt) o[dt] = zero4;
    f32x4 o4 = zero4;   // l accumulator (all rows identical)

    // preload K fragments for iteration 0
    bf16x8 kf[2][4];
#pragma unroll
    for (int hh = 0; hh < 2; ++hh)
#pragma unroll
        for (int kt = 0; kt < 4; ++kt)
            kf[hh][kt] = *(const bf16x8*)(kblk + (hh ? voff1 : voff0) + (kt << 7));

    for (int it = 0; it < 64; ++it) {
        // issue V loads early; consumed after S + softmax
        bf16x8 vf[2][4];
#pragma unroll
        for (int h2 = 0; h2 < 2; ++h2)
#pragma unroll
            for (int dt = 0; dt < 4; ++dt)
                vf[h2][dt] = *(const bf16x8*)(vblk + (h2 ? voff1 : voff0) + (dt << 7));

        // S^T[key][q] = K . Q^T
        f32x4 s[4];
#pragma unroll
        for (int kt = 0; kt < 4; ++kt) s[kt] = zero4;
#pragma unroll
        for (int hh = 0; hh < 2; ++hh)
#pragma unroll
            for (int kt = 0; kt < 4; ++kt)
                s[kt] = __builtin_amdgcn_mfma_f32_16x16x32_bf16(
                    kf[hh][kt], qf[hh], s[kt], 0, 0, 0);

        // P = exp2(S), pack to bf16 via v_perm truncation
#pragma unroll
        for (int kt = 0; kt < 4; ++kt) {
            f32x4 sv = s[kt];
            float e0 = EXP2(sv[0]), e1 = EXP2(sv[1]);
            float e2 = EXP2(sv[2]), e3 = EXP2(sv[3]);
            uint2 pk;
            pk.x = pktrunc(e0, e1);
            pk.y = pktrunc(e2, e3);
            *(uint2*)&Ps[w][l16][(((kt << 2) + quad) ^ (l7 << 1)) << 2] = pk;
        }

        // prefetch next K fragments (kf regs dead after S phase)
        if (it < 63) {
            const __bf16* knext = kblk + 4096;
#pragma unroll
            for (int hh = 0; hh < 2; ++hh)
#pragma unroll
                for (int kt = 0; kt < 4; ++kt)
                    kf[hh][kt] = *(const bf16x8*)(knext + (hh ? voff1 : voff0) + (kt << 7));
        }

        // O^T[d][q] += V^T . P^T ; l += ones . P^T
#pragma unroll
        for (int hh = 0; hh < 2; ++hh) {
            bf16x8 pf = *(const bf16x8*)&Ps[w][l16]
                          [(((hh << 3) + (quad << 1)) ^ (l7 << 1)) << 2];
#pragma unroll
            for (int dt = 0; dt < 4; ++dt)
                o[dt] = __builtin_amdgcn_mfma_f32_16x16x32_bf16(
                    vf[hh][dt], pf, o[dt], 0, 0, 0);
            o4 = __builtin_amdgcn_mfma_f32_16x16x32_bf16(ones, pf, o4, 0, 0, 0);
        }

        kblk += 4096;
        vblk += 4096;
    }

    // l(q=l16) sits in every row of o4 -> element 0 on every lane
    const float inv = 1.f / o4[0];

    // epilogue: attT[b][n][h*64+d] = o/l, bf16 (RNE)
    {
        int n = qw0 + l16;
        __bf16* dst = attT + ((size_t)b * N_ + n) * C_ + h * HD_ + (quad << 2);
#pragma unroll
        for (int dt = 0; dt < 4; ++dt) {
            uint2 pk;
            pk.x = f2bf(o[dt][0] * inv) | (f2bf(o[dt][1] * inv) << 16);
            pk.y = f2bf(o[dt][2] * inv) | (f2bf(o[dt][3] * inv) << 16);
            *(uint2*)(dst + (dt << 4)) = pk;
        }
    }
}

// ---------------------------------------------------------------------------
extern "C" void kernel_launch(void* const* d_in, const int* in_sizes, int n_in,
                              void* d_out, int out_size, void* d_ws, size_t ws_size,
                              hipStream_t stream) {
    const float* x      = (const float*)d_in[0];
    const float* norm_w = (const float*)d_in[1];
    const float* norm_b = (const float*)d_in[2];
    const float* qkv_w  = (const float*)d_in[3];
    const float* qkv_b  = (const float*)d_in[4];
    const float* proj_w = (const float*)d_in[5];
    const float* proj_b = (const float*)d_in[6];
    float* out = (float*)d_out;

    const size_t BCN = (size_t)B_ * C_ * N_;      // 4194304
    float* psum  = (float*)d_ws;                  // 256 floats
    float* psq   = psum + 256;                    // 256 floats
    __bf16* xnT  = (__bf16*)(psq + 256);          // [b][p][c]
    __bf16* qT   = xnT + BCN;                     // [bh][p][d]
    __bf16* kP   = qT + BCN;                      // blocked K''
    __bf16* vP   = kP + BCN;                      // blocked V''
    __bf16* attT = vP + BCN;                      // [b][n][c]
    __bf16* wq   = attT + BCN;                    // 1536x512
    __bf16* wp   = wq + (size_t)3 * C_ * C_;      // 512x512

    prep<<<1280, 256, 0, stream>>>(x, qkv_w, proj_w, psum, psq, wq, wp);
    gn_apply_t<<<dim3(N_ / 64, C_ / 64, B_), 256, 0, stream>>>(
        x, norm_w, norm_b, psum, psq, xnT);
    gemm_bf16<3 * C_, 0><<<dim3(N_ / 128, 3 * C_ / 128, B_), 256, 0, stream>>>(
        wq, xnT, qkv_b, nullptr, qT, kP, vP, nullptr);
    attn_mfma<<<dim3(N_ / 64, NH_, B_), 256, 0, stream>>>(qT, kP, vP, attT);
    gemm_bf16<C_, 1><<<dim3(N_ / 128, C_ / 128, B_), 256, 0, stream>>>(
        wp, attT, proj_b, x, nullptr, nullptr, nullptr, out);
}

// Round 10
// 248.189 us; speedup vs baseline: 1.0622x; 1.0622x over previous
//
#include <hip/hip_runtime.h>
#include <stdint.h>

#define B_   2
#define C_   512
#define N_   4096           // 64*64 pixels
#define G_   8
#define NH_  8
#define HD_  64
#define GRPELEMS ((C_ / G_) * N_)   // 262144 per (b, group)
#define NCHUNK 16                   // partial-reduce chunks per (b, group)

typedef __bf16 bf16x8 __attribute__((ext_vector_type(8)));
typedef float  f32x4  __attribute__((ext_vector_type(4)));

#if __has_builtin(__builtin_amdgcn_exp2f)
#define EXP2(x) __builtin_amdgcn_exp2f(x)
#else
#define EXP2(x) exp2f(x)
#endif

// fp32 -> bf16 round-to-nearest-even (finite inputs only)
__device__ inline unsigned f2bf(float f) {
    union { float f; unsigned u; } v; v.f = f;
    return (v.u + 0x7FFFu + ((v.u >> 16) & 1u)) >> 16;
}
__device__ inline __bf16 tobf(float f) {
    unsigned short u = (unsigned short)f2bf(f);
    union { unsigned short u; __bf16 b; } c; c.u = u;
    return c.b;
}
// pack hi16(f1):hi16(f0) in ONE v_perm_b32 (truncation to bf16)
__device__ inline unsigned pktrunc(float f0, float f1) {
    return __builtin_amdgcn_perm(__float_as_uint(f1), __float_as_uint(f0),
                                 0x07060302u);
}

// async global->LDS, 16B per lane; LDS dest = wave-uniform base + lane*16
#define GLOAD16(g, l)                                                     \
    __builtin_amdgcn_global_load_lds(                                     \
        (const __attribute__((address_space(1))) unsigned*)(g),           \
        (__attribute__((address_space(3))) unsigned*)(l), 16, 0, 0)

// ---------------------------------------------------------------------------
// prep: fused GroupNorm partial stats + weight bf16 conversion.
// ---------------------------------------------------------------------------
__global__ __launch_bounds__(256) void prep(const float* __restrict__ x,
                                            const float* __restrict__ qw,
                                            const float* __restrict__ pw,
                                            float* __restrict__ psum,
                                            float* __restrict__ psq,
                                            __bf16* __restrict__ dq,
                                            __bf16* __restrict__ dp) {
    const int blk = blockIdx.x;
    const int t = threadIdx.x;
    if (blk < 256) {
        const float4* p = (const float4*)x + (size_t)blk * 4096;
        float s = 0.f, s2 = 0.f;
#pragma unroll
        for (int i = 0; i < 16; ++i) {
            float4 v = p[t + (i << 8)];
            s  += v.x + v.y + v.z + v.w;
            s2 += v.x * v.x + v.y * v.y + v.z * v.z + v.w * v.w;
        }
#pragma unroll
        for (int off = 1; off < 64; off <<= 1) {
            s  += __shfl_xor(s, off);
            s2 += __shfl_xor(s2, off);
        }
        __shared__ float rs[4], rq[4];
        if ((t & 63) == 0) { rs[t >> 6] = s; rq[t >> 6] = s2; }
        __syncthreads();
        if (t == 0) {
            psum[blk] = rs[0] + rs[1] + rs[2] + rs[3];
            psq[blk]  = rq[0] + rq[1] + rq[2] + rq[3];
        }
    } else {
        const int QW4 = (3 * C_ * C_) / 4;   // 196608 float4s
        int idx = (blk - 256) * 256 + t;
        float4 v; __bf16* dst; int o;
        if (idx < QW4) { v = ((const float4*)qw)[idx]; dst = dq; o = idx; }
        else           { v = ((const float4*)pw)[idx - QW4]; dst = dp; o = idx - QW4; }
        uint2 pk;
        pk.x = f2bf(v.x) | (f2bf(v.y) << 16);
        pk.y = f2bf(v.z) | (f2bf(v.w) << 16);
        *(uint2*)(dst + (size_t)o * 4) = pk;
    }
}

// ---------------------------------------------------------------------------
// GroupNorm finalize + apply + transpose: x[b][c][p] fp32 -> xnT[b][p][c] bf16.
// ---------------------------------------------------------------------------
__global__ __launch_bounds__(256) void gn_apply_t(const float* __restrict__ x,
                                                  const float* __restrict__ w,
                                                  const float* __restrict__ bb,
                                                  const float* __restrict__ psum,
                                                  const float* __restrict__ psq,
                                                  __bf16* __restrict__ xnT) {
    const int p0 = blockIdx.x << 6, c0 = blockIdx.y << 6, b = blockIdx.z;
    __shared__ __bf16 T[64][76];   // row stride 152 B
    __shared__ float red[2 * NCHUNK];
    __shared__ float smr[2];
    const int tid = threadIdx.x;
    const int bg = b * G_ + (c0 >> 6);

    if (tid < NCHUNK)            red[tid] = psum[bg * NCHUNK + tid];
    else if (tid < 2 * NCHUNK)   red[tid] = psq[bg * NCHUNK + tid - NCHUNK];
    __syncthreads();
    if (tid == 0) {
        float s = 0.f, q = 0.f;
#pragma unroll
        for (int i = 0; i < NCHUNK; ++i) { s += red[i]; q += red[NCHUNK + i]; }
        const float inv = 1.f / (float)GRPELEMS;
        float mean = s * inv;
        float var  = q * inv - mean * mean;
        smr[0] = mean;
        smr[1] = rsqrtf(var + 1e-5f);
    }
    __syncthreads();
    const float mean = smr[0], rstd = smr[1];

    const int tr  = tid >> 4;
    const int tc4 = (tid & 15) << 2;
    const float* xb = x + ((size_t)b * C_ + c0) * N_ + p0;
#pragma unroll
    for (int cc = tr; cc < 64; cc += 16) {
        int c = c0 + cc;
        float sc = rstd * w[c];
        float sh = bb[c] - mean * sc;
        float4 v = *(const float4*)(xb + (size_t)cc * N_ + tc4);
        T[tc4 + 0][cc] = tobf(v.x * sc + sh);
        T[tc4 + 1][cc] = tobf(v.y * sc + sh);
        T[tc4 + 2][cc] = tobf(v.z * sc + sh);
        T[tc4 + 3][cc] = tobf(v.w * sc + sh);
    }
    __syncthreads();
    __bf16* dst = xnT + ((size_t)b * N_ + p0) * C_ + c0;
#pragma unroll
    for (int pp = tr; pp < 64; pp += 16)
        *(uint2*)(dst + (size_t)pp * C_ + tc4) = *(const uint2*)&T[pp][tc4];
}

// ---------------------------------------------------------------------------
// bf16 MFMA GEMM: C[o][p] = sum_c A[o][c]*Bm[b][p][c]
// EPI 0 epilogue writes MFMA-A-operand-ready BLOCKED K/V layouts (8 KB per
// 64-key block so the attn loop advances one uniform pointer per iter):
//   q: qT[bh][p][d]                      (pre-scaled)
//   k: kP[bh][key>>6][d>>3][key&63][8]   (granule = 8 d)
//   v: vP[bh][key>>6][(key>>3)&7][d][8]  (granule = 8 keys)
// ---------------------------------------------------------------------------
template <int M_TOTAL, int EPI>
__global__ __launch_bounds__(256) void gemm_bf16(const __bf16* __restrict__ A,
                                                 const __bf16* __restrict__ Bm,
                                                 const float* __restrict__ bias,
                                                 const float* __restrict__ resid,
                                                 __bf16* __restrict__ qT,
                                                 __bf16* __restrict__ kP,
                                                 __bf16* __restrict__ vP,
                                                 float* __restrict__ Y) {
    const int b  = blockIdx.z;
    const int M0 = blockIdx.y << 7;
    const int N0 = blockIdx.x << 7;
    const int tid = threadIdx.x;
    const int w = tid >> 6, lane = tid & 63;
    const int quad = lane >> 4, l16 = lane & 15;
    const int wr = w >> 1, wc = w & 1;

    __shared__ __bf16 As[128 * 64];
    __shared__ __bf16 Bs[128 * 64];

    const __bf16* Bb = Bm + (size_t)b * ((size_t)N_ * C_);

    const int srow = lane >> 3;
    const int sg   = lane & 7;

    f32x4 acc[4][4];
#pragma unroll
    for (int mt = 0; mt < 4; ++mt)
#pragma unroll
        for (int nt = 0; nt < 4; ++nt) acc[mt][nt] = (f32x4){0.f, 0.f, 0.f, 0.f};

    for (int k0 = 0; k0 < C_; k0 += 64) {
        __syncthreads();
#pragma unroll
        for (int i = 0; i < 4; ++i) {
            int r  = (w << 5) + (i << 3) + srow;
            int gc = ((sg ^ (r & 7)) << 3);
            const __bf16* ga = A  + (size_t)(M0 + r) * C_ + k0 + gc;
            const __bf16* gb = Bb + (size_t)(N0 + r) * C_ + k0 + gc;
            GLOAD16(ga, As + (((w << 2) + i) << 9));
            GLOAD16(gb, Bs + (((w << 2) + i) << 9));
        }
        __syncthreads();

#pragma unroll
        for (int kk = 0; kk < 2; ++kk) {
            bf16x8 af[4], bfr[4];
            const int gk = (kk << 2) + quad;
#pragma unroll
            for (int mt = 0; mt < 4; ++mt) {
                int m = (wr << 6) + (mt << 4) + l16;
                af[mt] = *(const bf16x8*)&As[(m << 6) + ((gk ^ (m & 7)) << 3)];
            }
#pragma unroll
            for (int nt = 0; nt < 4; ++nt) {
                int n = (wc << 6) + (nt << 4) + l16;
                bfr[nt] = *(const bf16x8*)&Bs[(n << 6) + ((gk ^ (n & 7)) << 3)];
            }
#pragma unroll
            for (int mt = 0; mt < 4; ++mt)
#pragma unroll
                for (int nt = 0; nt < 4; ++nt)
                    acc[mt][nt] = __builtin_amdgcn_mfma_f32_16x16x32_bf16(
                        af[mt], bfr[nt], acc[mt][nt], 0, 0, 0);
        }
    }

    if (EPI == 0) {
        const int t = M0 >> 9;
        const float sc = (t == 0) ? (0.125f * 1.44269504f) : 1.f;
#pragma unroll
        for (int mt = 0; mt < 4; ++mt) {
            const int o0 = M0 + (wr << 6) + (mt << 4) + (quad << 2);
            const int h  = (o0 >> 6) & 7;
            const int d0 = o0 & 63;
            const size_t bh = (size_t)b * NH_ + h;
            float bi[4];
#pragma unroll
            for (int r = 0; r < 4; ++r) bi[r] = bias[o0 + r];
            if (t == 0) {
                __bf16* dst = qT + (bh * N_) * HD_ + d0;
#pragma unroll
                for (int nt = 0; nt < 4; ++nt) {
                    int p = N0 + (wc << 6) + (nt << 4) + l16;
                    f32x4 v = acc[mt][nt];
                    uint2 pk;
                    pk.x = f2bf((v[0] + bi[0]) * sc) | (f2bf((v[1] + bi[1]) * sc) << 16);
                    pk.y = f2bf((v[2] + bi[2]) * sc) | (f2bf((v[3] + bi[3]) * sc) << 16);
                    *(uint2*)(dst + (size_t)p * HD_) = pk;
                }
            } else if (t == 1) {
                // K''[key>>6][d0>>3][key&63][8]; d0&7 in {0,4}
                __bf16* dst = kP + bh * ((size_t)N_ * HD_);
#pragma unroll
                for (int nt = 0; nt < 4; ++nt) {
                    int p = N0 + (wc << 6) + (nt << 4) + l16;
                    f32x4 v = acc[mt][nt];
                    uint2 pk;
                    pk.x = f2bf(v[0] + bi[0]) | (f2bf(v[1] + bi[1]) << 16);
                    pk.y = f2bf(v[2] + bi[2]) | (f2bf(v[3] + bi[3]) << 16);
                    size_t off = (size_t)(p >> 6) * 4096 +
                                 (size_t)((d0 >> 3) * 64 + (p & 63)) * 8 + (d0 & 7);
                    *(uint2*)(dst + off) = pk;
                }
            } else {
                // V''[key>>6][(key>>3)&7][d][8]
                __bf16* dst = vP + bh * ((size_t)HD_ * N_);
#pragma unroll
                for (int nt = 0; nt < 4; ++nt) {
                    int p = N0 + (wc << 6) + (nt << 4) + l16;
                    size_t base = (size_t)(p >> 6) * 4096 +
                                  (size_t)(((p >> 3) & 7) * 64) * 8 + (p & 7);
                    f32x4 v = acc[mt][nt];
#pragma unroll
                    for (int r = 0; r < 4; ++r)
                        dst[base + (size_t)(d0 + r) * 8] = tobf(v[r] + bi[r]);
                }
            }
        }
    } else {
#pragma unroll
        for (int mt = 0; mt < 4; ++mt) {
            const int o0 = M0 + (wr << 6) + (mt << 4) + (quad << 2);
            float bi[4];
#pragma unroll
            for (int r = 0; r < 4; ++r) bi[r] = bias[o0 + r];
#pragma unroll
            for (int nt = 0; nt < 4; ++nt) {
                int p = N0 + (wc << 6) + (nt << 4) + l16;
                f32x4 v = acc[mt][nt];
#pragma unroll
                for (int r = 0; r < 4; ++r) {
                    size_t off = ((size_t)b * C_ + o0 + r) * N_ + p;
                    Y[off] = v[r] + bi[r] + resid[off];
                }
            }
        }
    }
}

// ---------------------------------------------------------------------------
// MFMA flash attention v6 = v4 tile shape + v5 machinery.
//  32 q/wave, 4 waves/block (128 q/block) -> 2 GB total L2 K/V traffic.
//  Blocked K''/V'' operand layouts: one uniform +4096-elem pointer advance
//  per iter, loop-invariant lane voffsets (zero per-iter address VALU).
//  l via constant-ones-A MFMA on the packed P (zero VALU, consistent with
//  the truncated-P numerator). LDS: only per-wave Ps round-trip (16 KB).
// ---------------------------------------------------------------------------
__global__ __launch_bounds__(256) void attn_mfma(const __bf16* __restrict__ qT,
                                                 const __bf16* __restrict__ kP,
                                                 const __bf16* __restrict__ vP,
                                                 __bf16* __restrict__ attT) {
    const int tid  = threadIdx.x;
    const int w    = tid >> 6;
    const int lane = tid & 63;
    const int quad = lane >> 4;
    const int l16  = lane & 15;
    const int l7   = l16 & 7;
    const int h = blockIdx.y, b = blockIdx.z;
    const int qw0 = (blockIdx.x << 7) + (w << 5);   // 32 q per wave

    __shared__ __bf16 Ps[4][32][64];   // per-wave P^T [q][key], 8B-granule swz

    const size_t bh = (size_t)b * NH_ + h;
    const __bf16* qTb  = qT + bh * ((size_t)N_ * HD_);
    const __bf16* kblk = kP + bh * ((size_t)N_ * HD_);
    const __bf16* vblk = vP + bh * ((size_t)HD_ * N_);

    // loop-invariant lane voffsets into an 8 KB block (shared by K and V)
    const int voff0 = (quad * 64 + l16) * 8;         // hh/h2 = 0
    const int voff1 = ((4 + quad) * 64 + l16) * 8;   // hh/h2 = 1

    // Q fragments: persistent (q pre-scaled)
    bf16x8 qf[2][2];
#pragma unroll
    for (int qt = 0; qt < 2; ++qt)
#pragma unroll
        for (int hh = 0; hh < 2; ++hh)
            qf[qt][hh] = *(const bf16x8*)(qTb +
                (size_t)(qw0 + (qt << 4) + l16) * HD_ + (hh << 5) + (quad << 3));

    // constant ones A-fragment
    bf16x8 ones;
#pragma unroll
    for (int i = 0; i < 8; ++i) ones[i] = (__bf16)1.0f;

    const f32x4 zero4 = {0.f, 0.f, 0.f, 0.f};
    f32x4 o[4][2];
#pragma unroll
    for (int dt = 0; dt < 4; ++dt) { o[dt][0] = zero4; o[dt][1] = zero4; }
    f32x4 ol[2] = {zero4, zero4};   // l accumulators (all rows identical)

    // preload K fragments for iteration 0
    bf16x8 kf[2][4];
#pragma unroll
    for (int hh = 0; hh < 2; ++hh)
#pragma unroll
        for (int kt = 0; kt < 4; ++kt)
            kf[hh][kt] = *(const bf16x8*)(kblk + (hh ? voff1 : voff0) + (kt << 7));

    for (int it = 0; it < 64; ++it) {
        // issue V loads early; consumed after S + softmax
        bf16x8 vf[2][4];
#pragma unroll
        for (int h2 = 0; h2 < 2; ++h2)
#pragma unroll
            for (int dt = 0; dt < 4; ++dt)
                vf[h2][dt] = *(const bf16x8*)(vblk + (h2 ? voff1 : voff0) + (dt << 7));

        // S^T[key][q] = K . Q^T
        f32x4 s[4][2];
#pragma unroll
        for (int kt = 0; kt < 4; ++kt) { s[kt][0] = zero4; s[kt][1] = zero4; }
#pragma unroll
        for (int hh = 0; hh < 2; ++hh)
#pragma unroll
            for (int kt = 0; kt < 4; ++kt) {
                s[kt][0] = __builtin_amdgcn_mfma_f32_16x16x32_bf16(
                    kf[hh][kt], qf[0][hh], s[kt][0], 0, 0, 0);
                s[kt][1] = __builtin_amdgcn_mfma_f32_16x16x32_bf16(
                    kf[hh][kt], qf[1][hh], s[kt][1], 0, 0, 0);
            }

        // P = exp2(S), pack to bf16 via v_perm truncation
#pragma unroll
        for (int qt = 0; qt < 2; ++qt)
#pragma unroll
            for (int kt = 0; kt < 4; ++kt) {
                f32x4 sv = s[kt][qt];
                float e0 = EXP2(sv[0]), e1 = EXP2(sv[1]);
                float e2 = EXP2(sv[2]), e3 = EXP2(sv[3]);
                uint2 pk;
                pk.x = pktrunc(e0, e1);
                pk.y = pktrunc(e2, e3);
                *(uint2*)&Ps[w][(qt << 4) + l16]
                            [(((kt << 2) + quad) ^ (l7 << 1)) << 2] = pk;
            }

        // prefetch next K fragments (kf regs dead after S phase)
        if (it < 63) {
            const __bf16* knext = kblk + 4096;
#pragma unroll
            for (int hh = 0; hh < 2; ++hh)
#pragma unroll
                for (int kt = 0; kt < 4; ++kt)
                    kf[hh][kt] = *(const bf16x8*)(knext + (hh ? voff1 : voff0) + (kt << 7));
        }

        // O^T[d][q] += V^T . P^T ; l += ones . P^T
#pragma unroll
        for (int hh = 0; hh < 2; ++hh) {
            bf16x8 pf0 = *(const bf16x8*)&Ps[w][l16]
                          [(((hh << 3) + (quad << 1)) ^ (l7 << 1)) << 2];
            bf16x8 pf1 = *(const bf16x8*)&Ps[w][16 + l16]
                          [(((hh << 3) + (quad << 1)) ^ (l7 << 1)) << 2];
#pragma unroll
            for (int dt = 0; dt < 4; ++dt) {
                o[dt][0] = __builtin_amdgcn_mfma_f32_16x16x32_bf16(
                    vf[hh][dt], pf0, o[dt][0], 0, 0, 0);
                o[dt][1] = __builtin_amdgcn_mfma_f32_16x16x32_bf16(
                    vf[hh][dt], pf1, o[dt][1], 0, 0, 0);
            }
            ol[0] = __builtin_amdgcn_mfma_f32_16x16x32_bf16(ones, pf0, ol[0], 0, 0, 0);
            ol[1] = __builtin_amdgcn_mfma_f32_16x16x32_bf16(ones, pf1, ol[1], 0, 0, 0);
        }

        kblk += 4096;
        vblk += 4096;
    }

    // l(q) = ol[qt][0] on every lane (all D rows equal; col = l16 = q)
    // epilogue: attT[b][n][h*64+d] = o/l, bf16 (RNE)
#pragma unroll
    for (int qt = 0; qt < 2; ++qt) {
        float inv = 1.f / ol[qt][0];
        int n = qw0 + (qt << 4) + l16;
        __bf16* dst = attT + ((size_t)b * N_ + n) * C_ + h * HD_ + (quad << 2);
#pragma unroll
        for (int dt = 0; dt < 4; ++dt) {
            uint2 pk;
            pk.x = f2bf(o[dt][qt][0] * inv) | (f2bf(o[dt][qt][1] * inv) << 16);
            pk.y = f2bf(o[dt][qt][2] * inv) | (f2bf(o[dt][qt][3] * inv) << 16);
            *(uint2*)(dst + (dt << 4)) = pk;
        }
    }
}

// ---------------------------------------------------------------------------
extern "C" void kernel_launch(void* const* d_in, const int* in_sizes, int n_in,
                              void* d_out, int out_size, void* d_ws, size_t ws_size,
                              hipStream_t stream) {
    const float* x      = (const float*)d_in[0];
    const float* norm_w = (const float*)d_in[1];
    const float* norm_b = (const float*)d_in[2];
    const float* qkv_w  = (const float*)d_in[3];
    const float* qkv_b  = (const float*)d_in[4];
    const float* proj_w = (const float*)d_in[5];
    const float* proj_b = (const float*)d_in[6];
    float* out = (float*)d_out;

    const size_t BCN = (size_t)B_ * C_ * N_;      // 4194304
    float* psum  = (float*)d_ws;                  // 256 floats
    float* psq   = psum + 256;                    // 256 floats
    __bf16* xnT  = (__bf16*)(psq + 256);          // [b][p][c]
    __bf16* qT   = xnT + BCN;                     // [bh][p][d]
    __bf16* kP   = qT + BCN;                      // blocked K''
    __bf16* vP   = kP + BCN;                      // blocked V''
    __bf16* attT = vP + BCN;                      // [b][n][c]
    __bf16* wq   = attT + BCN;                    // 1536x512
    __bf16* wp   = wq + (size_t)3 * C_ * C_;      // 512x512

    prep<<<1280, 256, 0, stream>>>(x, qkv_w, proj_w, psum, psq, wq, wp);
    gn_apply_t<<<dim3(N_ / 64, C_ / 64, B_), 256, 0, stream>>>(
        x, norm_w, norm_b, psum, psq, xnT);
    gemm_bf16<3 * C_, 0><<<dim3(N_ / 128, 3 * C_ / 128, B_), 256, 0, stream>>>(
        wq, xnT, qkv_b, nullptr, qT, kP, vP, nullptr);
    attn_mfma<<<dim3(N_ / 128, NH_, B_), 256, 0, stream>>>(qT, kP, vP, attT);
    gemm_bf16<C_, 1><<<dim3(N_ / 128, C_ / 128, B_), 256, 0, stream>>>(
        wp, attT, proj_b, x, nullptr, nullptr, nullptr, out);
}

// Round 11
// 206.795 us; speedup vs baseline: 1.2748x; 1.2002x over previous
//
#include <hip/hip_runtime.h>
#include <stdint.h>

#define B_   2
#define C_   512
#define N_   4096           // 64*64 pixels
#define G_   8
#define NH_  8
#define HD_  64
#define GRPELEMS ((C_ / G_) * N_)   // 262144 per (b, group)
#define NCHUNK 16                   // partial-reduce chunks per (b, group)

typedef __bf16 bf16x8 __attribute__((ext_vector_type(8)));
typedef float  f32x4  __attribute__((ext_vector_type(4)));

#if __has_builtin(__builtin_amdgcn_exp2f)
#define EXP2(x) __builtin_amdgcn_exp2f(x)
#else
#define EXP2(x) exp2f(x)
#endif

// fp32 -> bf16 round-to-nearest-even (finite inputs only)
__device__ inline unsigned f2bf(float f) {
    union { float f; unsigned u; } v; v.f = f;
    return (v.u + 0x7FFFu + ((v.u >> 16) & 1u)) >> 16;
}
__device__ inline __bf16 tobf(float f) {
    unsigned short u = (unsigned short)f2bf(f);
    union { unsigned short u; __bf16 b; } c; c.u = u;
    return c.b;
}
// pack hi16(f1):hi16(f0) in ONE v_perm_b32 (truncation to bf16)
__device__ inline unsigned pktrunc(float f0, float f1) {
    return __builtin_amdgcn_perm(__float_as_uint(f1), __float_as_uint(f0),
                                 0x07060302u);
}
// truncate fp32 to bf16-precision fp32 (for l-sum consistency with packed P)
__device__ inline float trunc_bf(float f) {
    return __uint_as_float(__float_as_uint(f) & 0xffff0000u);
}

// async global->LDS, 16B per lane; LDS dest = wave-uniform base + lane*16
#define GLOAD16(g, l)                                                     \
    __builtin_amdgcn_global_load_lds(                                     \
        (const __attribute__((address_space(1))) unsigned*)(g),           \
        (__attribute__((address_space(3))) unsigned*)(l), 16, 0, 0)

// ---------------------------------------------------------------------------
// prep: fused GroupNorm partial stats + weight bf16 conversion.
// ---------------------------------------------------------------------------
__global__ __launch_bounds__(256) void prep(const float* __restrict__ x,
                                            const float* __restrict__ qw,
                                            const float* __restrict__ pw,
                                            float* __restrict__ psum,
                                            float* __restrict__ psq,
                                            __bf16* __restrict__ dq,
                                            __bf16* __restrict__ dp) {
    const int blk = blockIdx.x;
    const int t = threadIdx.x;
    if (blk < 256) {
        const float4* p = (const float4*)x + (size_t)blk * 4096;
        float s = 0.f, s2 = 0.f;
#pragma unroll
        for (int i = 0; i < 16; ++i) {
            float4 v = p[t + (i << 8)];
            s  += v.x + v.y + v.z + v.w;
            s2 += v.x * v.x + v.y * v.y + v.z * v.z + v.w * v.w;
        }
#pragma unroll
        for (int off = 1; off < 64; off <<= 1) {
            s  += __shfl_xor(s, off);
            s2 += __shfl_xor(s2, off);
        }
        __shared__ float rs[4], rq[4];
        if ((t & 63) == 0) { rs[t >> 6] = s; rq[t >> 6] = s2; }
        __syncthreads();
        if (t == 0) {
            psum[blk] = rs[0] + rs[1] + rs[2] + rs[3];
            psq[blk]  = rq[0] + rq[1] + rq[2] + rq[3];
        }
    } else {
        const int QW4 = (3 * C_ * C_) / 4;   // 196608 float4s
        int idx = (blk - 256) * 256 + t;
        float4 v; __bf16* dst; int o;
        if (idx < QW4) { v = ((const float4*)qw)[idx]; dst = dq; o = idx; }
        else           { v = ((const float4*)pw)[idx - QW4]; dst = dp; o = idx - QW4; }
        uint2 pk;
        pk.x = f2bf(v.x) | (f2bf(v.y) << 16);
        pk.y = f2bf(v.z) | (f2bf(v.w) << 16);
        *(uint2*)(dst + (size_t)o * 4) = pk;
    }
}

// ---------------------------------------------------------------------------
// GroupNorm finalize + apply + transpose: x[b][c][p] fp32 -> xnT[b][p][c] bf16.
// ---------------------------------------------------------------------------
__global__ __launch_bounds__(256) void gn_apply_t(const float* __restrict__ x,
                                                  const float* __restrict__ w,
                                                  const float* __restrict__ bb,
                                                  const float* __restrict__ psum,
                                                  const float* __restrict__ psq,
                                                  __bf16* __restrict__ xnT) {
    const int p0 = blockIdx.x << 6, c0 = blockIdx.y << 6, b = blockIdx.z;
    __shared__ __bf16 T[64][76];   // row stride 152 B
    __shared__ float red[2 * NCHUNK];
    __shared__ float smr[2];
    const int tid = threadIdx.x;
    const int bg = b * G_ + (c0 >> 6);

    if (tid < NCHUNK)            red[tid] = psum[bg * NCHUNK + tid];
    else if (tid < 2 * NCHUNK)   red[tid] = psq[bg * NCHUNK + tid - NCHUNK];
    __syncthreads();
    if (tid == 0) {
        float s = 0.f, q = 0.f;
#pragma unroll
        for (int i = 0; i < NCHUNK; ++i) { s += red[i]; q += red[NCHUNK + i]; }
        const float inv = 1.f / (float)GRPELEMS;
        float mean = s * inv;
        float var  = q * inv - mean * mean;
        smr[0] = mean;
        smr[1] = rsqrtf(var + 1e-5f);
    }
    __syncthreads();
    const float mean = smr[0], rstd = smr[1];

    const int tr  = tid >> 4;
    const int tc4 = (tid & 15) << 2;
    const float* xb = x + ((size_t)b * C_ + c0) * N_ + p0;
#pragma unroll
    for (int cc = tr; cc < 64; cc += 16) {
        int c = c0 + cc;
        float sc = rstd * w[c];
        float sh = bb[c] - mean * sc;
        float4 v = *(const float4*)(xb + (size_t)cc * N_ + tc4);
        T[tc4 + 0][cc] = tobf(v.x * sc + sh);
        T[tc4 + 1][cc] = tobf(v.y * sc + sh);
        T[tc4 + 2][cc] = tobf(v.z * sc + sh);
        T[tc4 + 3][cc] = tobf(v.w * sc + sh);
    }
    __syncthreads();
    __bf16* dst = xnT + ((size_t)b * N_ + p0) * C_ + c0;
#pragma unroll
    for (int pp = tr; pp < 64; pp += 16)
        *(uint2*)(dst + (size_t)pp * C_ + tc4) = *(const uint2*)&T[pp][tc4];
}

// ---------------------------------------------------------------------------
// bf16 MFMA GEMM, 64x128 tile (was 128x128): A-tile 8 KB + B-tile 16 KB,
// 4 waves in 2x2, each wave 2x4 16x16x32 microtiles. Smaller M-tile doubles
// the block count (qkv 1536 = 6/CU, proj 512 = 2/CU) so barrier drains in
// the short 8-iter K-loop overlap with co-resident blocks (m114 mechanism).
// EPI 0 epilogue writes attention operand layouts (r8-verified):
//   q: qT[bh][p][d] (pre-scaled)   k: K'[bh][d>>3][key][8]
//   v: V'[bh][key>>3][d][8]
// ---------------------------------------------------------------------------
template <int M_TOTAL, int EPI>
__global__ __launch_bounds__(256) void gemm_bf16(const __bf16* __restrict__ A,
                                                 const __bf16* __restrict__ Bm,
                                                 const float* __restrict__ bias,
                                                 const float* __restrict__ resid,
                                                 __bf16* __restrict__ qT,
                                                 __bf16* __restrict__ kP,
                                                 __bf16* __restrict__ vP,
                                                 float* __restrict__ Y) {
    const int b  = blockIdx.z;
    const int M0 = blockIdx.y << 6;        // 64-row tile
    const int N0 = blockIdx.x << 7;        // 128-col tile
    const int tid = threadIdx.x;
    const int w = tid >> 6, lane = tid & 63;
    const int quad = lane >> 4, l16 = lane & 15;
    const int wr = w >> 1, wc = w & 1;

    __shared__ __bf16 As[64 * 64];    // [m][k], XOR-swizzled granules, 8 KB
    __shared__ __bf16 Bs[128 * 64];   // [n][k], 16 KB

    const __bf16* Bb = Bm + (size_t)b * ((size_t)N_ * C_);

    const int srow = lane >> 3;
    const int sg   = lane & 7;

    f32x4 acc[2][4];
#pragma unroll
    for (int mt = 0; mt < 2; ++mt)
#pragma unroll
        for (int nt = 0; nt < 4; ++nt) acc[mt][nt] = (f32x4){0.f, 0.f, 0.f, 0.f};

    for (int k0 = 0; k0 < C_; k0 += 64) {
        __syncthreads();
#pragma unroll
        for (int i = 0; i < 2; ++i) {   // A: 64 rows, 2 groups/wave
            int r  = (w << 4) + (i << 3) + srow;
            int gc = ((sg ^ (r & 7)) << 3);
            GLOAD16(A + (size_t)(M0 + r) * C_ + k0 + gc, As + (((w << 1) + i) << 9));
        }
#pragma unroll
        for (int i = 0; i < 4; ++i) {   // B: 128 rows, 4 groups/wave
            int r  = (w << 5) + (i << 3) + srow;
            int gc = ((sg ^ (r & 7)) << 3);
            GLOAD16(Bb + (size_t)(N0 + r) * C_ + k0 + gc, Bs + (((w << 2) + i) << 9));
        }
        __syncthreads();

#pragma unroll
        for (int kk = 0; kk < 2; ++kk) {
            bf16x8 af[2], bfr[4];
            const int gk = (kk << 2) + quad;
#pragma unroll
            for (int mt = 0; mt < 2; ++mt) {
                int m = (wr << 5) + (mt << 4) + l16;
                af[mt] = *(const bf16x8*)&As[(m << 6) + ((gk ^ (m & 7)) << 3)];
            }
#pragma unroll
            for (int nt = 0; nt < 4; ++nt) {
                int n = (wc << 6) + (nt << 4) + l16;
                bfr[nt] = *(const bf16x8*)&Bs[(n << 6) + ((gk ^ (n & 7)) << 3)];
            }
#pragma unroll
            for (int mt = 0; mt < 2; ++mt)
#pragma unroll
                for (int nt = 0; nt < 4; ++nt)
                    acc[mt][nt] = __builtin_amdgcn_mfma_f32_16x16x32_bf16(
                        af[mt], bfr[nt], acc[mt][nt], 0, 0, 0);
        }
    }

    if (EPI == 0) {
        const int t = M0 >> 9;
        const float sc = (t == 0) ? (0.125f * 1.44269504f) : 1.f;
#pragma unroll
        for (int mt = 0; mt < 2; ++mt) {
            const int o0 = M0 + (wr << 5) + (mt << 4) + (quad << 2);
            const int h  = (o0 >> 6) & 7;
            const int d0 = o0 & 63;
            const size_t bh = (size_t)b * NH_ + h;
            float bi[4];
#pragma unroll
            for (int r = 0; r < 4; ++r) bi[r] = bias[o0 + r];
            if (t == 0) {
                __bf16* dst = qT + (bh * N_) * HD_ + d0;
#pragma unroll
                for (int nt = 0; nt < 4; ++nt) {
                    int p = N0 + (wc << 6) + (nt << 4) + l16;
                    f32x4 v = acc[mt][nt];
                    uint2 pk;
                    pk.x = f2bf((v[0] + bi[0]) * sc) | (f2bf((v[1] + bi[1]) * sc) << 16);
                    pk.y = f2bf((v[2] + bi[2]) * sc) | (f2bf((v[3] + bi[3]) * sc) << 16);
                    *(uint2*)(dst + (size_t)p * HD_) = pk;
                }
            } else if (t == 1) {
                // K'[d0>>3][key][8]; d0&7 in {0,4}
                __bf16* dst = kP + bh * ((size_t)N_ * HD_);
                const size_t kkbase = (size_t)(d0 >> 3) * N_;
                const int rem = d0 & 7;
#pragma unroll
                for (int nt = 0; nt < 4; ++nt) {
                    int p = N0 + (wc << 6) + (nt << 4) + l16;
                    f32x4 v = acc[mt][nt];
                    uint2 pk;
                    pk.x = f2bf(v[0] + bi[0]) | (f2bf(v[1] + bi[1]) << 16);
                    pk.y = f2bf(v[2] + bi[2]) | (f2bf(v[3] + bi[3]) << 16);
                    *(uint2*)(dst + (kkbase + p) * 8 + rem) = pk;
                }
            } else {
                // V'[p>>3][d][8]
                __bf16* dst = vP + bh * ((size_t)HD_ * N_);
#pragma unroll
                for (int nt = 0; nt < 4; ++nt) {
                    int p = N0 + (wc << 6) + (nt << 4) + l16;
                    const size_t gb2 = ((size_t)(p >> 3) * HD_) * 8 + (p & 7);
                    f32x4 v = acc[mt][nt];
#pragma unroll
                    for (int r = 0; r < 4; ++r)
                        dst[gb2 + (size_t)(d0 + r) * 8] = tobf(v[r] + bi[r]);
                }
            }
        }
    } else {
#pragma unroll
        for (int mt = 0; mt < 2; ++mt) {
            const int o0 = M0 + (wr << 5) + (mt << 4) + (quad << 2);
            float bi[4];
#pragma unroll
            for (int r = 0; r < 4; ++r) bi[r] = bias[o0 + r];
#pragma unroll
            for (int nt = 0; nt < 4; ++nt) {
                int p = N0 + (wc << 6) + (nt << 4) + l16;
                f32x4 v = acc[mt][nt];
#pragma unroll
                for (int r = 0; r < 4; ++r) {
                    size_t off = ((size_t)b * C_ + o0 + r) * N_ + p;
                    Y[off] = v[r] + bi[r] + resid[off];
                }
            }
        }
    }
}

// ---------------------------------------------------------------------------
// MFMA flash attention v4 (r8-verified, 102.7 us): no barriers, no K/V LDS.
//  - K/V A-fragments read directly from L2-resident K'/V' operand layouts
//    (coalesced dwordx4); register double-buffer for K (next-iter prefetch).
//  - l accumulated in VALU from bf16-truncated P (consistent with packed P).
//  - LDS holds only the verified per-wave Ps round-trip (16 KB).
// Do not perturb: r9 (16q) hit the L2-traffic wall (2x reads), r10 (blocked
// layouts + ones-MFMA) stalled on bursty lockstep L2 access. This is the
// measured local optimum of the loop structure.
// ---------------------------------------------------------------------------
__global__ __launch_bounds__(256) void attn_mfma(const __bf16* __restrict__ qT,
                                                 const __bf16* __restrict__ kP,
                                                 const __bf16* __restrict__ vP,
                                                 __bf16* __restrict__ attT) {
    const int tid  = threadIdx.x;
    const int w    = tid >> 6;
    const int lane = tid & 63;
    const int quad = lane >> 4;
    const int l16  = lane & 15;
    const int l7   = l16 & 7;
    const int h = blockIdx.y, b = blockIdx.z;
    const int qw0 = (blockIdx.x << 7) + (w << 5);   // 32 q per wave

    __shared__ __bf16 Ps[4][32][64];   // per-wave P^T [q][key], 8B-granule swz

    const size_t bh = (size_t)b * NH_ + h;
    const __bf16* qTb = qT + bh * ((size_t)N_ * HD_);
    const __bf16* kPb = kP + bh * ((size_t)N_ * HD_);
    const __bf16* vPb = vP + bh * ((size_t)HD_ * N_);

    // Q fragments: persistent across the whole k-loop (q pre-scaled)
    bf16x8 qf[2][2];
#pragma unroll
    for (int qt = 0; qt < 2; ++qt)
#pragma unroll
        for (int hh = 0; hh < 2; ++hh)
            qf[qt][hh] = *(const bf16x8*)(qTb +
                (size_t)(qw0 + (qt << 4) + l16) * HD_ + (hh << 5) + (quad << 3));

#define KADDR(hh, kt, kb) (kPb + (((size_t)((hh << 2) + quad) * N_) + (kb) + ((kt) << 4) + l16) * 8)
#define VADDR(h2, dt, kb) (vPb + (((size_t)(((kb) >> 3) + ((h2) << 2) + quad) * HD_) + ((dt) << 4) + l16) * 8)

    const f32x4 zero4 = {0.f, 0.f, 0.f, 0.f};
    f32x4 o[4][2];
#pragma unroll
    for (int dt = 0; dt < 4; ++dt) { o[dt][0] = zero4; o[dt][1] = zero4; }
    float lacc[2] = {0.f, 0.f};

    // preload K fragments for iteration 0
    bf16x8 kf[2][4];
#pragma unroll
    for (int hh = 0; hh < 2; ++hh)
#pragma unroll
        for (int kt = 0; kt < 4; ++kt)
            kf[hh][kt] = *(const bf16x8*)KADDR(hh, kt, 0);

    for (int it = 0; it < 64; ++it) {
        const int kb = it << 6;

        // issue V loads early; consumed after S + softmax (latency hidden)
        bf16x8 vf[2][4];
#pragma unroll
        for (int h2 = 0; h2 < 2; ++h2)
#pragma unroll
            for (int dt = 0; dt < 4; ++dt)
                vf[h2][dt] = *(const bf16x8*)VADDR(h2, dt, kb);

        // S^T[key][q] = K . Q^T
        f32x4 s[4][2];
#pragma unroll
        for (int kt = 0; kt < 4; ++kt) { s[kt][0] = zero4; s[kt][1] = zero4; }
#pragma unroll
        for (int hh = 0; hh < 2; ++hh)
#pragma unroll
            for (int kt = 0; kt < 4; ++kt) {
                s[kt][0] = __builtin_amdgcn_mfma_f32_16x16x32_bf16(
                    kf[hh][kt], qf[0][hh], s[kt][0], 0, 0, 0);
                s[kt][1] = __builtin_amdgcn_mfma_f32_16x16x32_bf16(
                    kf[hh][kt], qf[1][hh], s[kt][1], 0, 0, 0);
            }

        // P = exp2(S); l += truncated P; pack to bf16 via v_perm truncation
#pragma unroll
        for (int qt = 0; qt < 2; ++qt)
#pragma unroll
            for (int kt = 0; kt < 4; ++kt) {
                f32x4 sv = s[kt][qt];
                float e0 = EXP2(sv[0]), e1 = EXP2(sv[1]);
                float e2 = EXP2(sv[2]), e3 = EXP2(sv[3]);
                lacc[qt] += (trunc_bf(e0) + trunc_bf(e1)) +
                            (trunc_bf(e2) + trunc_bf(e3));
                uint2 pk;
                pk.x = pktrunc(e0, e1);
                pk.y = pktrunc(e2, e3);
                *(uint2*)&Ps[w][(qt << 4) + l16]
                            [(((kt << 2) + quad) ^ (l7 << 1)) << 2] = pk;
            }

        // prefetch next K fragments (register double-buffer)
        if (it < 63) {
#pragma unroll
            for (int hh = 0; hh < 2; ++hh)
#pragma unroll
                for (int kt = 0; kt < 4; ++kt)
                    kf[hh][kt] = *(const bf16x8*)KADDR(hh, kt, kb + 64);
        }

        // O^T[d][q] += V^T . P^T
#pragma unroll
        for (int hh = 0; hh < 2; ++hh) {
            bf16x8 pf0 = *(const bf16x8*)&Ps[w][l16]
                          [(((hh << 3) + (quad << 1)) ^ (l7 << 1)) << 2];
            bf16x8 pf1 = *(const bf16x8*)&Ps[w][16 + l16]
                          [(((hh << 3) + (quad << 1)) ^ (l7 << 1)) << 2];
#pragma unroll
            for (int dt = 0; dt < 4; ++dt) {
                o[dt][0] = __builtin_amdgcn_mfma_f32_16x16x32_bf16(
                    vf[hh][dt], pf0, o[dt][0], 0, 0, 0);
                o[dt][1] = __builtin_amdgcn_mfma_f32_16x16x32_bf16(
                    vf[hh][dt], pf1, o[dt][1], 0, 0, 0);
            }
        }
    }

    // l: lane holds 16-key partial per qt; butterfly over lane bits 4,5
    float lq[2];
#pragma unroll
    for (int qt = 0; qt < 2; ++qt) {
        float v = lacc[qt];
        v += __shfl_xor(v, 16);
        v += __shfl_xor(v, 32);
        lq[qt] = v;
    }

    // epilogue: attT[b][n][h*64+d] = o/l, bf16 (RNE)
#pragma unroll
    for (int qt = 0; qt < 2; ++qt) {
        float inv = 1.f / lq[qt];
        int n = qw0 + (qt << 4) + l16;
        __bf16* dst = attT + ((size_t)b * N_ + n) * C_ + h * HD_ + (quad << 2);
#pragma unroll
        for (int dt = 0; dt < 4; ++dt) {
            uint2 pk;
            pk.x = f2bf(o[dt][qt][0] * inv) | (f2bf(o[dt][qt][1] * inv) << 16);
            pk.y = f2bf(o[dt][qt][2] * inv) | (f2bf(o[dt][qt][3] * inv) << 16);
            *(uint2*)(dst + (dt << 4)) = pk;
        }
    }
#undef KADDR
#undef VADDR
}

// ---------------------------------------------------------------------------
extern "C" void kernel_launch(void* const* d_in, const int* in_sizes, int n_in,
                              void* d_out, int out_size, void* d_ws, size_t ws_size,
                              hipStream_t stream) {
    const float* x      = (const float*)d_in[0];
    const float* norm_w = (const float*)d_in[1];
    const float* norm_b = (const float*)d_in[2];
    const float* qkv_w  = (const float*)d_in[3];
    const float* qkv_b  = (const float*)d_in[4];
    const float* proj_w = (const float*)d_in[5];
    const float* proj_b = (const float*)d_in[6];
    float* out = (float*)d_out;

    const size_t BCN = (size_t)B_ * C_ * N_;      // 4194304
    float* psum  = (float*)d_ws;                  // 256 floats
    float* psq   = psum + 256;                    // 256 floats
    __bf16* xnT  = (__bf16*)(psq + 256);          // [b][p][c]
    __bf16* qT   = xnT + BCN;                     // [bh][p][d]
    __bf16* kP   = qT + BCN;                      // K' [bh][d>>3][key][8]
    __bf16* vP   = kP + BCN;                      // V' [bh][key>>3][d][8]
    __bf16* attT = vP + BCN;                      // [b][n][c]
    __bf16* wq   = attT + BCN;                    // 1536x512
    __bf16* wp   = wq + (size_t)3 * C_ * C_;      // 512x512

    prep<<<1280, 256, 0, stream>>>(x, qkv_w, proj_w, psum, psq, wq, wp);
    gn_apply_t<<<dim3(N_ / 64, C_ / 64, B_), 256, 0, stream>>>(
        x, norm_w, norm_b, psum, psq, xnT);
    gemm_bf16<3 * C_, 0><<<dim3(N_ / 128, 3 * C_ / 64, B_), 256, 0, stream>>>(
        wq, xnT, qkv_b, nullptr, qT, kP, vP, nullptr);
    attn_mfma<<<dim3(N_ / 128, NH_, B_), 256, 0, stream>>>(qT, kP, vP, attT);
    gemm_bf16<C_, 1><<<dim3(N_ / 128, C_ / 64, B_), 256, 0, stream>>>(
        wp, attT, proj_b, x, nullptr, nullptr, nullptr, out);
}